// Round 10
// baseline (146.533 us; speedup 1.0000x reference)
//
#include <hip/hip_runtime.h>
#include <hip/hip_bf16.h>
#include <stdint.h>

// Problem constants
#define B_  2
#define S_  2048
#define D_  1024
#define H_  16
#define DQ_ 64
#define QT_ (S_/64)   // 32 q-tiles (64 rows each) per (b,h)

// softmax is shift-invariant -> no max subtraction needed at all.
// scale folded into Q pack: qb = bf16(q * 0.125 * log2(e)), P = exp2(K·qb)
#define C1_ 0.18033688011112042f   // 0.125 * log2(e)

typedef float f32x4  __attribute__((ext_vector_type(4)));
typedef float f32x16 __attribute__((ext_vector_type(16)));
typedef short bf16x8 __attribute__((ext_vector_type(8)));

#define MFMA32(A,B,C) __builtin_amdgcn_mfma_f32_32x32x16_bf16(A,B,C,0,0,0)

__device__ __forceinline__ unsigned short f2bf(float f) {
    uint32_t u = __float_as_uint(f);
    u += 0x7fffu + ((u >> 16) & 1u);   // round-to-nearest-even
    return (unsigned short)(u >> 16);
}
__device__ __forceinline__ float bf2f(unsigned short u) {
    return __uint_as_float(((uint32_t)u) << 16);
}
__device__ __forceinline__ float fast_exp2(float x) {
#if __has_builtin(__builtin_amdgcn_exp2f)
    return __builtin_amdgcn_exp2f(x);
#else
    float r; asm("v_exp_f32 %0, %1" : "=v"(r) : "v"(x)); return r;
#endif
}
__device__ __forceinline__ uint32_t cvt_pk_bf16(float lo, float hi) {
    uint32_t r;
    asm("v_cvt_pk_bf16_f32 %0, %1, %2" : "=v"(r) : "v"(lo), "v"(hi));
    return r;
}
// vdst[32..63] <-> vsrc[0..31]
__device__ __forceinline__ void permlane32_swap(uint32_t &a, uint32_t &b) {
    asm volatile("v_permlane32_swap_b32 %0, %1" : "+v"(a), "+v"(b));
}

// ---------------------------------------------------------------------------
// Kernel 1: prep (unchanged from R9). K/V -> exact 32x32x16 fragment order
// via LDS-staged transpose; Wo fp32->bf16; Pv partials for row-0 mean(V).
// ---------------------------------------------------------------------------
__global__ __launch_bounds__(256) void prep_kernel(
    const float* __restrict__ K, const float* __restrict__ V,
    const float* __restrict__ W,
    unsigned short* __restrict__ Kf, unsigned short* __restrict__ Vf,
    unsigned short* __restrict__ Wb, float* __restrict__ Pv)
{
    __shared__ unsigned short Ls[64][72];
    __shared__ float Pp[8][64];
    const int blk = blockIdx.x, tid = threadIdx.x;

    if (blk < 2048) {
        const bool isV = blk < 1024;
        const int gb = isV ? blk : (blk - 1024);
        const int g = gb >> 5, j = gb & 31;
        const int b = g >> 4, h = g & 15;
        const float* src0 = (isV ? V : K) + ((size_t)(b*S_ + j*64))*D_ + h*64;

        // phase A: coalesced tile load (64 rows x 64 cols fp32) -> bf16 LDS
        {
            int row = tid >> 2, col0 = (tid & 3) * 16;
            const float* src = src0 + (size_t)row*D_ + col0;
            float4 f0 = ((const float4*)src)[0];
            float4 f1 = ((const float4*)src)[1];
            float4 f2 = ((const float4*)src)[2];
            float4 f3 = ((const float4*)src)[3];
            unsigned short* d = &Ls[row][col0];
            d[0]=f2bf(f0.x); d[1]=f2bf(f0.y); d[2]=f2bf(f0.z); d[3]=f2bf(f0.w);
            d[4]=f2bf(f1.x); d[5]=f2bf(f1.y); d[6]=f2bf(f1.z); d[7]=f2bf(f1.w);
            d[8]=f2bf(f2.x); d[9]=f2bf(f2.y); d[10]=f2bf(f2.z); d[11]=f2bf(f2.w);
            d[12]=f2bf(f3.x); d[13]=f2bf(f3.y); d[14]=f2bf(f3.z); d[15]=f2bf(f3.w);
        }
        __syncthreads();

        if (isV) {
            // phase B: transpose via LDS scalar reads -> coalesced frag stores
            #pragma unroll
            for (int ps = 0; ps < 2; ++ps) {
                const int slot = tid + ps*256;
                const int fb = slot >> 6, l = slot & 63;
                const int s = fb >> 1, kk = fb & 1;
                const int hi = l >> 5, l31 = l & 31;
                const int dcol = kk*32 + l31;
                unsigned short us[8];
                float p = 0.f;
                #pragma unroll
                for (int r = 0; r < 8; ++r) {
                    unsigned short u = Ls[s*16 + hi*8 + r][dcol];
                    us[r] = u;
                    p += bf2f(u);
                }
                *(uint4*)(Vf + ((size_t)gb*8 + fb)*512 + (size_t)l*8) = *(uint4*)us;
                Pp[s*2 + hi][dcol] = p;
            }
            __syncthreads();
            if (tid < 64) {
                float t = 0.f;
                #pragma unroll
                for (int i = 0; i < 8; ++i) t += Pp[i][tid];
                Pv[((size_t)g*64 + tid)*32 + j] = t;
            }
        } else {
            // phase B: rows are fragment-contiguous -> b128 LDS reads
            #pragma unroll
            for (int ps = 0; ps < 2; ++ps) {
                const int slot = tid + ps*256;
                const int fb = slot >> 6, l = slot & 63;
                const int wk = fb >> 2, s = fb & 3;
                const int hi = l >> 5, l31 = l & 31;
                uint4 val = *(const uint4*)&Ls[wk*32 + l31][s*16 + hi*8];
                *(uint4*)(Kf + ((size_t)gb*8 + fb)*512 + (size_t)l*8) = val;
            }
        }
    } else {
        int i = (blk - 2048)*256 + tid;     // < D*D/4 = 262144
        float4 f = ((const float4*)W)[i];
        ushort4 o;
        o.x = f2bf(f.x); o.y = f2bf(f.y); o.z = f2bf(f.z); o.w = f2bf(f.w);
        ((ushort4*)Wb)[i] = o;
    }
}

// ---------------------------------------------------------------------------
// Kernel 2: flash attention, 32x32x16 MFMA, zero-LDS main loop.
// R10: HALVE VMEM TRAFFIC. R6/R8/R9 falsified occupancy/chain/prefetch as
// the bound; remaining shared resource is L2 BW (~15.6us floor at the old
// 2.1MB/CU, duplicated between the two wq waves). Now: block = 128 thr =
// 2 waves (wk = key half); EACH WAVE DOES ALL 64 q-rows (subtiles a/b via
// qfa/qfb) against its 32-key half -> same 8KB loads feed 16 MFMAs
// (arithmetic intensity 2x, per-CU traffic 1.05MB, L2 floor ~8us).
// Register budget: single 4-deep QK chain (R8: split gains nothing),
// depth-2 prefetch (R9: depth-3 gains nothing) -> ~212 VGPR < 256 cap of
// launch_bounds(128,2). Spill tripwire: WRITE_SIZE must stay ~8.2MB.
// Diagonal tile j==qt: wk=1 skips subtile a (fully masked); masked-exp
// test is kr >= l31 for both (wk=0,a) and (wk=1,b); (wk=0,b) unmasked.
// Retained: longest-first balanced qt map, Q staged via LDS, setprio,
// shift-free softmax, bid&7 XCD affinity, single end barrier.
// ---------------------------------------------------------------------------
__global__ __launch_bounds__(128, 2) void attn_kernel(
    const float* __restrict__ Q,
    const unsigned short* __restrict__ Kf,
    const unsigned short* __restrict__ Vf,
    const float* __restrict__ Pv,
    unsigned short* __restrict__ ctx,
    const int* __restrict__ maskp)
{
    __shared__ union {
        unsigned short qs[64][72];                    // Q staging (prologue)
        struct { float osum[2][32][68]; float lsum[2][32]; } red;  // epilogue
    } sm;

    const int bid = blockIdx.x;
    const int g = bid & 31;             // h + 16*b ; g&7 = bid&7 -> XCD
    const int p = bid >> 5;             // [0,32)
    // longest-first balanced permutation: octiles -> qt {31..24,16..23,15..8,0..7}
    const int qt = (p < 8) ? 31 - p : (p < 16) ? p + 8 : (p < 24) ? 31 - p : p - 24;
    const int h = g & 15, b = g >> 4;
    const int tid  = threadIdx.x;
    const int wk   = tid >> 6;          // wave = key half
    const int lane = tid & 63;
    const int hi = lane >> 5, l31 = lane & 31;
    const int maskv = maskp[0];

    // fused mean(V) -> ctx row 0, cols [h*64, h*64+64)
    if (maskv && qt == 0 && tid < 64) {
        const float* pv = Pv + ((size_t)g*64 + tid)*32;
        float s = 0.f;
        #pragma unroll
        for (int i = 0; i < 32; ++i) s += pv[i];
        ctx[(size_t)b*S_*D_ + h*64 + tid] = f2bf(s * (1.0f/S_));
    }

    // ---- stage Q tile (coalesced) -> LDS as pre-scaled bf16 ----
    #pragma unroll
    for (int ps = 0; ps < 2; ++ps) {
        const int slot = tid + ps*128;                 // 0..255
        const int row = slot >> 2, col0 = (slot & 3) * 16;
        const float* src = Q + ((size_t)(b*S_ + qt*64 + row))*D_ + h*64 + col0;
        float4 f0 = ((const float4*)src)[0];
        float4 f1 = ((const float4*)src)[1];
        float4 f2 = ((const float4*)src)[2];
        float4 f3 = ((const float4*)src)[3];
        unsigned short* d = &sm.qs[row][col0];
        d[0]=f2bf(f0.x*C1_); d[1]=f2bf(f0.y*C1_); d[2]=f2bf(f0.z*C1_); d[3]=f2bf(f0.w*C1_);
        d[4]=f2bf(f1.x*C1_); d[5]=f2bf(f1.y*C1_); d[6]=f2bf(f1.z*C1_); d[7]=f2bf(f1.w*C1_);
        d[8]=f2bf(f2.x*C1_); d[9]=f2bf(f2.y*C1_); d[10]=f2bf(f2.z*C1_); d[11]=f2bf(f2.w*C1_);
        d[12]=f2bf(f3.x*C1_); d[13]=f2bf(f3.y*C1_); d[14]=f2bf(f3.z*C1_); d[15]=f2bf(f3.w*C1_);
    }
    __syncthreads();
    bf16x8 qfa[4], qfb[4];
    #pragma unroll
    for (int s = 0; s < 4; ++s) {
        qfa[s] = *(const bf16x8*)&sm.qs[l31][s*16 + hi*8];        // q rows 0..31
        qfb[s] = *(const bf16x8*)&sm.qs[32 + l31][s*16 + hi*8];   // q rows 32..63
    }
    __syncthreads();   // Qs reads done before epilogue aliases the buffer

    // fragment bases (advance by j*4096 ushorts per tile)
    const unsigned short* kfb =
        Kf + ((size_t)g*32*8 + wk*4)*512 + (size_t)lane*8;
    const unsigned short* vfb =
        Vf + ((size_t)g*32*8 + wk*4)*512 + (size_t)lane*8;

    const int njw = maskv ? (qt + 1) : QT_;

    // O accumulators: subtile a/b x d-halves
    f32x16 oa0 = {}, oa1 = {}, ob0 = {}, ob1 = {};
    float lsa = 0.f, lsb = 0.f;

    // ---- depth-2 prefetch: static ping-pong buffers (no runtime idx)
    bf16x8 ka[4], va[4], kb[4], vb[4];
    if (njw > 0) {
        #pragma unroll
        for (int s = 0; s < 4; ++s) {
            ka[s] = *(const bf16x8*)(kfb + s*512);
            va[s] = *(const bf16x8*)(vfb + s*512);
        }
    }
    if (njw > 1) {
        #pragma unroll
        for (int s = 0; s < 4; ++s) {
            kb[s] = *(const bf16x8*)(kfb + 4096 + s*512);
            vb[s] = *(const bf16x8*)(vfb + 4096 + s*512);
        }
    }

#define PACK_PV(E, O0, O1, VC)                                                \
    {                                                                         \
      uint32_t p01_ = cvt_pk_bf16(E[0], E[1]),  p23_ = cvt_pk_bf16(E[2], E[3]); \
      uint32_t p45_ = cvt_pk_bf16(E[4], E[5]),  p67_ = cvt_pk_bf16(E[6], E[7]); \
      permlane32_swap(p01_, p45_); permlane32_swap(p23_, p67_);               \
      uint32_t r01_ = cvt_pk_bf16(E[8], E[9]),  r23_ = cvt_pk_bf16(E[10], E[11]); \
      uint32_t r45_ = cvt_pk_bf16(E[12], E[13]), r67_ = cvt_pk_bf16(E[14], E[15]); \
      permlane32_swap(r01_, r45_); permlane32_swap(r23_, r67_);               \
      union { uint32_t u[4]; bf16x8 v; } A0_, A1_;                            \
      A0_.u[0]=p01_; A0_.u[1]=p23_; A0_.u[2]=p45_; A0_.u[3]=p67_;             \
      A1_.u[0]=r01_; A1_.u[1]=r23_; A1_.u[2]=r45_; A1_.u[3]=r67_;             \
      __builtin_amdgcn_s_setprio(1);                                          \
      O0 = MFMA32(A0_.v, VC[0], O0);                                          \
      O1 = MFMA32(A0_.v, VC[1], O1);                                          \
      O0 = MFMA32(A1_.v, VC[2], O0);                                          \
      O1 = MFMA32(A1_.v, VC[3], O1);                                          \
      __builtin_amdgcn_s_setprio(0);                                          \
    }

#define AITER(J, KC, VC)                                                      \
  {                                                                           \
    const bool diagJ_ = maskv && ((J) == qt);                                 \
    /* ---- subtile a (q rows 0..31): fully masked for wk==1 on diag ---- */  \
    if (!(diagJ_ && wk == 1)) {                                               \
      f32x16 st_ = {};                                                        \
      __builtin_amdgcn_s_setprio(1);                                          \
      st_ = MFMA32(KC[0], qfa[0], st_);                                       \
      st_ = MFMA32(KC[1], qfa[1], st_);                                       \
      st_ = MFMA32(KC[2], qfa[2], st_);                                       \
      st_ = MFMA32(KC[3], qfa[3], st_);                                       \
      __builtin_amdgcn_s_setprio(0);                                          \
      float e[16];                                                            \
      if (diagJ_) {            /* wk==0: mask key kr >= q l31 */              \
        _Pragma("unroll")                                                     \
        for (int r = 0; r < 16; ++r) {                                        \
          int kr_ = (r&3) + 8*(r>>2) + 4*hi;                                  \
          float ev_ = fast_exp2(st_[r]);                                      \
          e[r] = (kr_ >= l31) ? 0.f : ev_;                                    \
          lsa += e[r];                                                        \
        }                                                                     \
      } else {                                                                \
        _Pragma("unroll")                                                     \
        for (int r = 0; r < 16; ++r) { e[r] = fast_exp2(st_[r]); lsa += e[r]; } \
      }                                                                       \
      PACK_PV(e, oa0, oa1, VC)                                                \
    }                                                                         \
    /* ---- subtile b (q rows 32..63) ---- */                                 \
    {                                                                         \
      f32x16 st_ = {};                                                        \
      __builtin_amdgcn_s_setprio(1);                                          \
      st_ = MFMA32(KC[0], qfb[0], st_);                                       \
      st_ = MFMA32(KC[1], qfb[1], st_);                                       \
      st_ = MFMA32(KC[2], qfb[2], st_);                                       \
      st_ = MFMA32(KC[3], qfb[3], st_);                                       \
      __builtin_amdgcn_s_setprio(0);                                          \
      if ((J) + 2 < njw) {   /* K last use done: reload for j+2 */            \
        const unsigned short* kp_ = kfb + (size_t)((J)+2)*4096;               \
        KC[0] = *(const bf16x8*)(kp_);                                        \
        KC[1] = *(const bf16x8*)(kp_ + 512);                                  \
        KC[2] = *(const bf16x8*)(kp_ + 1024);                                 \
        KC[3] = *(const bf16x8*)(kp_ + 1536);                                 \
      }                                                                       \
      float e[16];                                                            \
      if (diagJ_ && wk == 1) { /* mask key kr >= q l31 (offsets cancel) */    \
        _Pragma("unroll")                                                     \
        for (int r = 0; r < 16; ++r) {                                        \
          int kr_ = (r&3) + 8*(r>>2) + 4*hi;                                  \
          float ev_ = fast_exp2(st_[r]);                                      \
          e[r] = (kr_ >= l31) ? 0.f : ev_;                                    \
          lsb += e[r];                                                        \
        }                                                                     \
      } else {                                                                \
        _Pragma("unroll")                                                     \
        for (int r = 0; r < 16; ++r) { e[r] = fast_exp2(st_[r]); lsb += e[r]; } \
      }                                                                       \
      PACK_PV(e, ob0, ob1, VC)                                                \
      if ((J) + 2 < njw) {   /* V last use done: reload for j+2 */            \
        const unsigned short* vp_ = vfb + (size_t)((J)+2)*4096;               \
        VC[0] = *(const bf16x8*)(vp_);                                        \
        VC[1] = *(const bf16x8*)(vp_ + 512);                                  \
        VC[2] = *(const bf16x8*)(vp_ + 1024);                                 \
        VC[3] = *(const bf16x8*)(vp_ + 1536);                                 \
      }                                                                       \
    }                                                                         \
  }

    int j = 0;
    for (; j + 1 < njw; j += 2) {
        AITER(j,   ka, va);
        AITER(j+1, kb, vb);
    }
    if (j < njw) AITER(j, ka, va);
#undef AITER
#undef PACK_PV

    // ---- cross-wk reduction + epilogue (one barrier) ----
    lsa += __shfl_xor(lsa, 32);   // combine hi key sub-slots: l for q=l31
    lsb += __shfl_xor(lsb, 32);

    if (wk == 1) {
        #pragma unroll
        for (int r = 0; r < 16; ++r) {
            int qr = (r&3) + 8*(r>>2) + 4*hi;
            sm.red.osum[0][qr][l31]      = oa0[r];
            sm.red.osum[0][qr][32 + l31] = oa1[r];
            sm.red.osum[1][qr][l31]      = ob0[r];
            sm.red.osum[1][qr][32 + l31] = ob1[r];
        }
        if (hi == 0) { sm.red.lsum[0][l31] = lsa; sm.red.lsum[1][l31] = lsb; }
    }
    __syncthreads();
    if (wk == 0) {
        float inva = 1.0f / (lsa + sm.red.lsum[0][l31]);   // inv for q = l31 (sub a)
        float invb = 1.0f / (lsb + sm.red.lsum[1][l31]);   // (sub b)
        #pragma unroll
        for (int r = 0; r < 16; ++r) {
            int qr = (r&3) + 8*(r>>2) + 4*hi;
            float a0v = oa0[r] + sm.red.osum[0][qr][l31];
            float a1v = oa1[r] + sm.red.osum[0][qr][32 + l31];
            float b0v = ob0[r] + sm.red.osum[1][qr][l31];
            float b1v = ob1[r] + sm.red.osum[1][qr][32 + l31];
            float invra = __shfl(inva, qr);
            float invrb = __shfl(invb, qr);
            int qa = qt*64 + qr;
            int qb = qt*64 + 32 + qr;
            if (!(maskv && qa == 0)) {   // row 0 = mean(V), done above
                size_t base = ((size_t)(b*S_ + qa))*D_ + h*64;
                ctx[base + l31]      = f2bf(a0v * invra);
                ctx[base + 32 + l31] = f2bf(a1v * invra);
            }
            {
                size_t base = ((size_t)(b*S_ + qb))*D_ + h*64;
                ctx[base + l31]      = f2bf(b0v * invrb);
                ctx[base + 32 + l31] = f2bf(b1v * invrb);
            }
        }
    }
}

// ---------------------------------------------------------------------------
// Kernel 3: out = ctx @ Wo^T + bias   (M=4096, N=1024, K=1024, bf16 MFMA)
// 64x128 tile, 4 waves (each 64x32), BK=64, double-buffered, 1 barrier/kt.
// Grid (8, 64) = 512 blocks -> 2 blocks/CU; bid%8 = nt0 -> each XCD caches
// exactly one 128-col Wo panel (0.25 MB).
// ---------------------------------------------------------------------------
__global__ __launch_bounds__(256, 2) void proj_kernel(
    const unsigned short* __restrict__ A,    // ctx bf16 [4096][1024]
    const unsigned short* __restrict__ Bw,   // Wo bf16  [1024][1024]
    const float* __restrict__ bias,
    float* __restrict__ out)
{
    __shared__ unsigned short As[2][64][72];
    __shared__ unsigned short Bs[2][128][72];
    const int nt0 = blockIdx.x;   // 0..7   (N panel)
    const int mt0 = blockIdx.y;   // 0..63  (M panel)
    const int tid  = threadIdx.x;
    const int wave = tid >> 6, lane = tid & 63;
    const int quad = lane >> 4, ln = lane & 15;

    const int arow = tid >> 2, acol = (tid & 3)*16;   // A: 64 rows x 64 cols
    const int brow = tid >> 1, bcol = (tid & 1)*32;   // B: 128 rows x 64 cols
    const unsigned short* aptr = A  + ((size_t)(mt0*64  + arow)*1024 + acol);
    const unsigned short* bptr = Bw + ((size_t)(nt0*128 + brow)*1024 + bcol);

    uint4 a0 = ((const uint4*)aptr)[0], a1 = ((const uint4*)aptr)[1];
    uint4 b0 = ((const uint4*)bptr)[0], b1 = ((const uint4*)bptr)[1],
          b2 = ((const uint4*)bptr)[2], b3 = ((const uint4*)bptr)[3];

    f32x4 acc[4][2] = {};

    for (int kt = 0; kt < 16; ++kt) {
        const int cur = kt & 1;
        *((uint4*)&As[cur][arow][acol])    = a0;
        *((uint4*)&As[cur][arow][acol+8])  = a1;
        *((uint4*)&Bs[cur][brow][bcol])    = b0;
        *((uint4*)&Bs[cur][brow][bcol+8])  = b1;
        *((uint4*)&Bs[cur][brow][bcol+16]) = b2;
        *((uint4*)&Bs[cur][brow][bcol+24]) = b3;
        uint4 na0, na1, nb0, nb1, nb2, nb3;
        if (kt < 15) {
            const unsigned short* ap = aptr + (kt+1)*64;
            const unsigned short* bp = bptr + (kt+1)*64;
            na0 = ((const uint4*)ap)[0]; na1 = ((const uint4*)ap)[1];
            nb0 = ((const uint4*)bp)[0]; nb1 = ((const uint4*)bp)[1];
            nb2 = ((const uint4*)bp)[2]; nb3 = ((const uint4*)bp)[3];
        }
        __syncthreads();
        #pragma unroll
        for (int ks = 0; ks < 2; ++ks) {
            bf16x8 am[4], bn[2];
            #pragma unroll
            for (int i = 0; i < 4; ++i)
                am[i] = *(const bf16x8*)&As[cur][i*16 + ln][ks*32 + quad*8];
            #pragma unroll
            for (int i = 0; i < 2; ++i)
                bn[i] = *(const bf16x8*)&Bs[cur][wave*32 + i*16 + ln][ks*32 + quad*8];
            #pragma unroll
            for (int mi = 0; mi < 4; ++mi)
                #pragma unroll
                for (int ni = 0; ni < 2; ++ni)
                    acc[mi][ni] = __builtin_amdgcn_mfma_f32_16x16x32_bf16(
                        am[mi], bn[ni], acc[mi][ni], 0,0,0);
        }
        a0 = na0; a1 = na1;
        b0 = nb0; b1 = nb1; b2 = nb2; b3 = nb3;
    }

    #pragma unroll
    for (int mi = 0; mi < 4; ++mi)
        #pragma unroll
        for (int ni = 0; ni < 2; ++ni) {
            int row = mt0*64 + mi*16 + quad*4;
            int col = nt0*128 + wave*32 + ni*16 + ln;
            float bv = bias[col];
            #pragma unroll
            for (int r = 0; r < 4; ++r)
                out[(size_t)(row + r)*1024 + col] = acc[mi][ni][r] + bv;
        }
}

// ---------------------------------------------------------------------------
extern "C" void kernel_launch(void* const* d_in, const int* in_sizes, int n_in,
                              void* d_out, int out_size, void* d_ws, size_t ws_size,
                              hipStream_t stream)
{
    const float* Q   = (const float*)d_in[0];
    const float* K   = (const float*)d_in[1];
    const float* V   = (const float*)d_in[2];
    const float* Wo  = (const float*)d_in[3];
    const float* Wb  = (const float*)d_in[4];
    const int* maskp = (const int*)d_in[5];
    float* out = (float*)d_out;

    // workspace layout (ushort units)
    unsigned short* Kf   = (unsigned short*)d_ws;              // 8.39 MB
    unsigned short* Vf   = Kf  + (size_t)B_*S_*D_;             // 8.39 MB
    unsigned short* Wob  = Vf  + (size_t)B_*S_*D_;             // 2.10 MB
    unsigned short* ctxb = Wob + (size_t)D_*D_;                // 8.39 MB
    float* Pv = (float*)(ctxb + (size_t)B_*S_*D_);             // 0.26 MB

    prep_kernel<<<3072, 256, 0, stream>>>(K, V, Wo, Kf, Vf, Wob, Pv);
    attn_kernel<<<1024, 128, 0, stream>>>(Q, Kf, Vf, Pv, ctxb, maskp);
    proj_kernel<<<dim3(8, 64), 256, 0, stream>>>(ctxb, Wob, Wb, out);
}

// Round 11
// 145.970 us; speedup vs baseline: 1.0039x; 1.0039x over previous
//
#include <hip/hip_runtime.h>
#include <hip/hip_bf16.h>
#include <stdint.h>

// Problem constants
#define B_  2
#define S_  2048
#define D_  1024
#define H_  16
#define DQ_ 64
#define QT_ (S_/64)   // 32 q-tiles (64 rows each) per (b,h)

// softmax is shift-invariant -> no max subtraction needed at all.
// scale folded into Q pack: qb = bf16(q * 0.125 * log2(e)), P = exp2(K·qb)
#define C1_ 0.18033688011112042f   // 0.125 * log2(e)

typedef float f32x4  __attribute__((ext_vector_type(4)));
typedef float f32x16 __attribute__((ext_vector_type(16)));
typedef short bf16x8 __attribute__((ext_vector_type(8)));

#define MFMA32(A,B,C) __builtin_amdgcn_mfma_f32_32x32x16_bf16(A,B,C,0,0,0)

__device__ __forceinline__ unsigned short f2bf(float f) {
    uint32_t u = __float_as_uint(f);
    u += 0x7fffu + ((u >> 16) & 1u);   // round-to-nearest-even
    return (unsigned short)(u >> 16);
}
__device__ __forceinline__ float bf2f(unsigned short u) {
    return __uint_as_float(((uint32_t)u) << 16);
}
__device__ __forceinline__ float fast_exp2(float x) {
#if __has_builtin(__builtin_amdgcn_exp2f)
    return __builtin_amdgcn_exp2f(x);
#else
    float r; asm("v_exp_f32 %0, %1" : "=v"(r) : "v"(x)); return r;
#endif
}
__device__ __forceinline__ uint32_t cvt_pk_bf16(float lo, float hi) {
    uint32_t r;
    asm("v_cvt_pk_bf16_f32 %0, %1, %2" : "=v"(r) : "v"(lo), "v"(hi));
    return r;
}
// vdst[32..63] <-> vsrc[0..31]
__device__ __forceinline__ void permlane32_swap(uint32_t &a, uint32_t &b) {
    asm volatile("v_permlane32_swap_b32 %0, %1" : "+v"(a), "+v"(b));
}

// ---------------------------------------------------------------------------
// Kernel 1: prep (unchanged from R9). K/V -> exact 32x32x16 fragment order
// via LDS-staged transpose; Wo fp32->bf16; Pv partials for row-0 mean(V).
// ---------------------------------------------------------------------------
__global__ __launch_bounds__(256) void prep_kernel(
    const float* __restrict__ K, const float* __restrict__ V,
    const float* __restrict__ W,
    unsigned short* __restrict__ Kf, unsigned short* __restrict__ Vf,
    unsigned short* __restrict__ Wb, float* __restrict__ Pv)
{
    __shared__ unsigned short Ls[64][72];
    __shared__ float Pp[8][64];
    const int blk = blockIdx.x, tid = threadIdx.x;

    if (blk < 2048) {
        const bool isV = blk < 1024;
        const int gb = isV ? blk : (blk - 1024);
        const int g = gb >> 5, j = gb & 31;
        const int b = g >> 4, h = g & 15;
        const float* src0 = (isV ? V : K) + ((size_t)(b*S_ + j*64))*D_ + h*64;

        // phase A: coalesced tile load (64 rows x 64 cols fp32) -> bf16 LDS
        {
            int row = tid >> 2, col0 = (tid & 3) * 16;
            const float* src = src0 + (size_t)row*D_ + col0;
            float4 f0 = ((const float4*)src)[0];
            float4 f1 = ((const float4*)src)[1];
            float4 f2 = ((const float4*)src)[2];
            float4 f3 = ((const float4*)src)[3];
            unsigned short* d = &Ls[row][col0];
            d[0]=f2bf(f0.x); d[1]=f2bf(f0.y); d[2]=f2bf(f0.z); d[3]=f2bf(f0.w);
            d[4]=f2bf(f1.x); d[5]=f2bf(f1.y); d[6]=f2bf(f1.z); d[7]=f2bf(f1.w);
            d[8]=f2bf(f2.x); d[9]=f2bf(f2.y); d[10]=f2bf(f2.z); d[11]=f2bf(f2.w);
            d[12]=f2bf(f3.x); d[13]=f2bf(f3.y); d[14]=f2bf(f3.z); d[15]=f2bf(f3.w);
        }
        __syncthreads();

        if (isV) {
            // phase B: transpose via LDS scalar reads -> coalesced frag stores
            #pragma unroll
            for (int ps = 0; ps < 2; ++ps) {
                const int slot = tid + ps*256;
                const int fb = slot >> 6, l = slot & 63;
                const int s = fb >> 1, kk = fb & 1;
                const int hi = l >> 5, l31 = l & 31;
                const int dcol = kk*32 + l31;
                unsigned short us[8];
                float p = 0.f;
                #pragma unroll
                for (int r = 0; r < 8; ++r) {
                    unsigned short u = Ls[s*16 + hi*8 + r][dcol];
                    us[r] = u;
                    p += bf2f(u);
                }
                *(uint4*)(Vf + ((size_t)gb*8 + fb)*512 + (size_t)l*8) = *(uint4*)us;
                Pp[s*2 + hi][dcol] = p;
            }
            __syncthreads();
            if (tid < 64) {
                float t = 0.f;
                #pragma unroll
                for (int i = 0; i < 8; ++i) t += Pp[i][tid];
                Pv[((size_t)g*64 + tid)*32 + j] = t;
            }
        } else {
            // phase B: rows are fragment-contiguous -> b128 LDS reads
            #pragma unroll
            for (int ps = 0; ps < 2; ++ps) {
                const int slot = tid + ps*256;
                const int fb = slot >> 6, l = slot & 63;
                const int wk = fb >> 2, s = fb & 3;
                const int hi = l >> 5, l31 = l & 31;
                uint4 val = *(const uint4*)&Ls[wk*32 + l31][s*16 + hi*8];
                *(uint4*)(Kf + ((size_t)gb*8 + fb)*512 + (size_t)l*8) = val;
            }
        }
    } else {
        int i = (blk - 2048)*256 + tid;     // < D*D/4 = 262144
        float4 f = ((const float4*)W)[i];
        ushort4 o;
        o.x = f2bf(f.x); o.y = f2bf(f.y); o.z = f2bf(f.z); o.w = f2bf(f.w);
        ((ushort4*)Wb)[i] = o;
    }
}

// ---------------------------------------------------------------------------
// Kernel 2: flash attention, 32x32x16 MFMA, zero-LDS main loop.
// R11: CROSS-ITERATION ILP. R6/R8/R9/R10 falsified occupancy / chain depth /
// prefetch distance / L2 traffic. The remaining model: each iteration's
// serial load->QK->exp->pack->PV chain (~1500cy wall vs ~400 busy). Fix:
// hand-interleave the two independent iterations of each unrolled pair:
//   QK-A + QK-B interleaved (8 indep MFMAs fill the pipe)
//   -> expA/packA (stA long done) -> PV-A (MFMA, runs in background)
//   -> expB/packB (VALU, overlaps PV-A) -> PV-B
// Every dependence edge now has the other iteration's work as slack.
// Also: pointer pre-increment (kfj/vfj += 8192 per pair) kills the runtime
// (j+2)*4096 64-bit address arithmetic on the 8 reloads.
// Retained from R9: 4 waves (wq,wk), one q-tile/block, grid 1024,
// longest-first balanced qt map, Q staged via LDS, setprio, shift-free
// softmax, per-wave causal niter, bid&7 XCD affinity, 1 barrier,
// 4 independent PV accumulators.
// launch_bounds (256,2): do NOT raise the 2nd arg (R4/R5: allocator spill).
// Spill tripwire: attn WRITE_SIZE must stay ~8.2MB.
// ---------------------------------------------------------------------------
__global__ __launch_bounds__(256, 2) void attn_kernel(
    const float* __restrict__ Q,
    const unsigned short* __restrict__ Kf,
    const unsigned short* __restrict__ Vf,
    const float* __restrict__ Pv,
    unsigned short* __restrict__ ctx,
    const int* __restrict__ maskp)
{
    __shared__ union {
        unsigned short qs[64][72];                    // Q staging (prologue)
        struct { float osum[2][32][68]; float lsum[2][32]; } red;  // epilogue
    } sm;

    const int bid = blockIdx.x;
    const int g = bid & 31;             // h + 16*b ; g&7 = bid&7 -> XCD
    const int p = bid >> 5;             // [0,32)
    // longest-first balanced permutation: octiles -> qt {31..24,16..23,15..8,0..7}
    const int qt = (p < 8) ? 31 - p : (p < 16) ? p + 8 : (p < 24) ? 31 - p : p - 24;
    const int h = g & 15, b = g >> 4;
    const int tid  = threadIdx.x;
    const int wave = tid >> 6, lane = tid & 63;
    const int wq = wave >> 1, wk = wave & 1;
    const int hi = lane >> 5, l31 = lane & 31;
    const int maskv = maskp[0];

    // fused mean(V) -> ctx row 0, cols [h*64, h*64+64)
    if (maskv && qt == 0 && tid < 64) {
        const float* pv = Pv + ((size_t)g*64 + tid)*32;
        float s = 0.f;
        #pragma unroll
        for (int i = 0; i < 32; ++i) s += pv[i];
        ctx[(size_t)b*S_*D_ + h*64 + tid] = f2bf(s * (1.0f/S_));
    }

    // ---- stage Q tile (coalesced) -> LDS as pre-scaled bf16 ----
    {
        const int row = tid >> 2, col0 = (tid & 3) * 16;
        const float* src = Q + ((size_t)(b*S_ + qt*64 + row))*D_ + h*64 + col0;
        float4 f0 = ((const float4*)src)[0];
        float4 f1 = ((const float4*)src)[1];
        float4 f2 = ((const float4*)src)[2];
        float4 f3 = ((const float4*)src)[3];
        unsigned short* d = &sm.qs[row][col0];
        d[0]=f2bf(f0.x*C1_); d[1]=f2bf(f0.y*C1_); d[2]=f2bf(f0.z*C1_); d[3]=f2bf(f0.w*C1_);
        d[4]=f2bf(f1.x*C1_); d[5]=f2bf(f1.y*C1_); d[6]=f2bf(f1.z*C1_); d[7]=f2bf(f1.w*C1_);
        d[8]=f2bf(f2.x*C1_); d[9]=f2bf(f2.y*C1_); d[10]=f2bf(f2.z*C1_); d[11]=f2bf(f2.w*C1_);
        d[12]=f2bf(f3.x*C1_); d[13]=f2bf(f3.y*C1_); d[14]=f2bf(f3.z*C1_); d[15]=f2bf(f3.w*C1_);
    }
    __syncthreads();
    bf16x8 qf[4];
    #pragma unroll
    for (int s = 0; s < 4; ++s)
        qf[s] = *(const bf16x8*)&sm.qs[wq*32 + l31][s*16 + hi*8];
    __syncthreads();   // Qs reads done before epilogue aliases the buffer

    // fragment bases (tile stride = 4096 ushorts)
    const unsigned short* kfb =
        Kf + ((size_t)g*32*8 + wk*4)*512 + (size_t)lane*8;
    const unsigned short* vfb =
        Vf + ((size_t)g*32*8 + wk*4)*512 + (size_t)lane*8;

    int njw = maskv ? (qt + 1) : QT_;
    if (maskv && wq == 0 && wk == 1) njw = qt;  // diagonal tile fully masked

    // 4 independent PV accumulators (summed in the epilogue)
    f32x16 o00 = {}, o01 = {}, o10 = {}, o11 = {};
    float lsum0 = 0.f, lsum1 = 0.f;

    // ---- depth-2 prefetch: static ping-pong buffers (no runtime idx)
    bf16x8 ka[4], va[4], kb[4], vb[4];
    if (njw > 0) {
        #pragma unroll
        for (int s = 0; s < 4; ++s) {
            ka[s] = *(const bf16x8*)(kfb + s*512);
            va[s] = *(const bf16x8*)(vfb + s*512);
        }
    }
    if (njw > 1) {
        #pragma unroll
        for (int s = 0; s < 4; ++s) {
            kb[s] = *(const bf16x8*)(kfb + 4096 + s*512);
            vb[s] = *(const bf16x8*)(vfb + 4096 + s*512);
        }
    }
    // prefetch cursors (pre-incremented; no runtime mul in the loop)
    const unsigned short* kfj = kfb + 8192;
    const unsigned short* vfj = vfb + 8192;

#define EXPBLK(ST, E, LS, DIAG)                                               \
    if (DIAG) {                                                               \
      _Pragma("unroll")                                                       \
      for (int r = 0; r < 16; ++r) {                                          \
        int kr_ = (r&3) + 8*(r>>2) + 4*hi;                                    \
        float ev_ = fast_exp2(ST[r]);                                         \
        E[r] = (kr_ >= l31) ? 0.f : ev_;                                      \
        LS += E[r];                                                           \
      }                                                                       \
    } else {                                                                  \
      _Pragma("unroll")                                                       \
      for (int r = 0; r < 16; ++r) { E[r] = fast_exp2(ST[r]); LS += E[r]; }   \
    }

#define PACKBLK(E, A0, A1)                                                    \
    {                                                                         \
      uint32_t p01_ = cvt_pk_bf16(E[0], E[1]),  p23_ = cvt_pk_bf16(E[2], E[3]); \
      uint32_t p45_ = cvt_pk_bf16(E[4], E[5]),  p67_ = cvt_pk_bf16(E[6], E[7]); \
      permlane32_swap(p01_, p45_); permlane32_swap(p23_, p67_);               \
      uint32_t r01_ = cvt_pk_bf16(E[8], E[9]),  r23_ = cvt_pk_bf16(E[10], E[11]); \
      uint32_t r45_ = cvt_pk_bf16(E[12], E[13]), r67_ = cvt_pk_bf16(E[14], E[15]); \
      permlane32_swap(r01_, r45_); permlane32_swap(r23_, r67_);               \
      A0.u[0]=p01_; A0.u[1]=p23_; A0.u[2]=p45_; A0.u[3]=p67_;                 \
      A1.u[0]=r01_; A1.u[1]=r23_; A1.u[2]=r45_; A1.u[3]=r67_;                 \
    }

    int j = 0;
    for (; j + 1 < njw; j += 2) {
        const bool diagA = maskv && (j == qt) && (wk == wq);
        const bool diagB = maskv && (j + 1 == qt) && (wk == wq);

        // ---- QK for BOTH iterations, interleaved (8 independent MFMAs) ----
        f32x16 stA = {}, stB = {};
        __builtin_amdgcn_s_setprio(1);
        stA = MFMA32(ka[0], qf[0], stA);
        stB = MFMA32(kb[0], qf[0], stB);
        stA = MFMA32(ka[1], qf[1], stA);
        stB = MFMA32(kb[1], qf[1], stB);
        stA = MFMA32(ka[2], qf[2], stA);
        stB = MFMA32(kb[2], qf[2], stB);
        stA = MFMA32(ka[3], qf[3], stA);
        stB = MFMA32(kb[3], qf[3], stB);
        __builtin_amdgcn_s_setprio(0);

        // ---- K reloads for j+2 / j+3 (buffers free; addresses = cursor) ----
        if (j + 2 < njw) {
            ka[0] = *(const bf16x8*)(kfj);
            ka[1] = *(const bf16x8*)(kfj + 512);
            ka[2] = *(const bf16x8*)(kfj + 1024);
            ka[3] = *(const bf16x8*)(kfj + 1536);
        }
        if (j + 3 < njw) {
            kb[0] = *(const bf16x8*)(kfj + 4096);
            kb[1] = *(const bf16x8*)(kfj + 4608);
            kb[2] = *(const bf16x8*)(kfj + 5120);
            kb[3] = *(const bf16x8*)(kfj + 5632);
        }

        // ---- iteration A: exp -> pack -> PV (PV runs in MFMA pipe) ----
        float eA[16];
        EXPBLK(stA, eA, lsum0, diagA)
        union { uint32_t u[4]; bf16x8 v; } A0a, A1a;
        PACKBLK(eA, A0a, A1a)
        __builtin_amdgcn_s_setprio(1);
        o00 = MFMA32(A0a.v, va[0], o00);
        o10 = MFMA32(A0a.v, va[1], o10);
        o01 = MFMA32(A1a.v, va[2], o01);
        o11 = MFMA32(A1a.v, va[3], o11);
        __builtin_amdgcn_s_setprio(0);

        // ---- iteration B: exp/pack VALU overlaps PV-A execution ----
        float eB[16];
        EXPBLK(stB, eB, lsum1, diagB)
        union { uint32_t u[4]; bf16x8 v; } A0b, A1b;
        PACKBLK(eB, A0b, A1b)
        __builtin_amdgcn_s_setprio(1);
        o00 = MFMA32(A0b.v, vb[0], o00);
        o10 = MFMA32(A0b.v, vb[1], o10);
        o01 = MFMA32(A1b.v, vb[2], o01);
        o11 = MFMA32(A1b.v, vb[3], o11);
        __builtin_amdgcn_s_setprio(0);

        // ---- V reloads for j+2 / j+3; advance cursors ----
        if (j + 2 < njw) {
            va[0] = *(const bf16x8*)(vfj);
            va[1] = *(const bf16x8*)(vfj + 512);
            va[2] = *(const bf16x8*)(vfj + 1024);
            va[3] = *(const bf16x8*)(vfj + 1536);
        }
        if (j + 3 < njw) {
            vb[0] = *(const bf16x8*)(vfj + 4096);
            vb[1] = *(const bf16x8*)(vfj + 4608);
            vb[2] = *(const bf16x8*)(vfj + 5120);
            vb[3] = *(const bf16x8*)(vfj + 5632);
        }
        kfj += 8192;
        vfj += 8192;
    }

    // ---- tail (njw odd): single iteration, tile j is in ka/va ----
    if (j < njw) {
        const bool diagA = maskv && (j == qt) && (wk == wq);
        f32x16 stA = {};
        __builtin_amdgcn_s_setprio(1);
        stA = MFMA32(ka[0], qf[0], stA);
        stA = MFMA32(ka[1], qf[1], stA);
        stA = MFMA32(ka[2], qf[2], stA);
        stA = MFMA32(ka[3], qf[3], stA);
        __builtin_amdgcn_s_setprio(0);
        float eA[16];
        EXPBLK(stA, eA, lsum0, diagA)
        union { uint32_t u[4]; bf16x8 v; } A0a, A1a;
        PACKBLK(eA, A0a, A1a)
        __builtin_amdgcn_s_setprio(1);
        o00 = MFMA32(A0a.v, va[0], o00);
        o10 = MFMA32(A0a.v, va[1], o10);
        o01 = MFMA32(A1a.v, va[2], o01);
        o11 = MFMA32(A1a.v, va[3], o11);
        __builtin_amdgcn_s_setprio(0);
    }
#undef EXPBLK
#undef PACKBLK

    f32x16 o0 = o00 + o01;     // combine split PV accumulators (d low half)
    f32x16 o1 = o10 + o11;     // (d high half)
    float lsum = lsum0 + lsum1;

    // ---- cross-wk reduction + epilogue (one barrier) ----
    lsum += __shfl_xor(lsum, 32);   // combine hi/lo key quads: l for q=l31

    if (wk == 1) {
        #pragma unroll
        for (int r = 0; r < 16; ++r) {
            int qr = (r&3) + 8*(r>>2) + 4*hi;
            sm.red.osum[wq][qr][l31]      = o0[r];
            sm.red.osum[wq][qr][32 + l31] = o1[r];
        }
        if (hi == 0) sm.red.lsum[wq][l31] = lsum;
    }
    __syncthreads();
    if (wk == 0) {
        float inv = 1.0f / (lsum + sm.red.lsum[wq][l31]);   // inv for q = l31
        #pragma unroll
        for (int r = 0; r < 16; ++r) {
            int qr = (r&3) + 8*(r>>2) + 4*hi;
            float o0v = o0[r] + sm.red.osum[wq][qr][l31];
            float o1v = o1[r] + sm.red.osum[wq][qr][32 + l31];
            float invr = __shfl(inv, qr);
            int q = qt*64 + wq*32 + qr;
            if (!(maskv && q == 0)) {   // row 0 = mean(V), done above
                size_t base = ((size_t)(b*S_ + q))*D_ + h*64;
                ctx[base + l31]      = f2bf(o0v * invr);
                ctx[base + 32 + l31] = f2bf(o1v * invr);
            }
        }
    }
}

// ---------------------------------------------------------------------------
// Kernel 3: out = ctx @ Wo^T + bias   (M=4096, N=1024, K=1024, bf16 MFMA)
// 64x128 tile, 4 waves (each 64x32), BK=64, double-buffered, 1 barrier/kt.
// Grid (8, 64) = 512 blocks -> 2 blocks/CU; bid%8 = nt0 -> each XCD caches
// exactly one 128-col Wo panel (0.25 MB).
// ---------------------------------------------------------------------------
__global__ __launch_bounds__(256, 2) void proj_kernel(
    const unsigned short* __restrict__ A,    // ctx bf16 [4096][1024]
    const unsigned short* __restrict__ Bw,   // Wo bf16  [1024][1024]
    const float* __restrict__ bias,
    float* __restrict__ out)
{
    __shared__ unsigned short As[2][64][72];
    __shared__ unsigned short Bs[2][128][72];
    const int nt0 = blockIdx.x;   // 0..7   (N panel)
    const int mt0 = blockIdx.y;   // 0..63  (M panel)
    const int tid  = threadIdx.x;
    const int wave = tid >> 6, lane = tid & 63;
    const int quad = lane >> 4, ln = lane & 15;

    const int arow = tid >> 2, acol = (tid & 3)*16;   // A: 64 rows x 64 cols
    const int brow = tid >> 1, bcol = (tid & 1)*32;   // B: 128 rows x 64 cols
    const unsigned short* aptr = A  + ((size_t)(mt0*64  + arow)*1024 + acol);
    const unsigned short* bptr = Bw + ((size_t)(nt0*128 + brow)*1024 + bcol);

    uint4 a0 = ((const uint4*)aptr)[0], a1 = ((const uint4*)aptr)[1];
    uint4 b0 = ((const uint4*)bptr)[0], b1 = ((const uint4*)bptr)[1],
          b2 = ((const uint4*)bptr)[2], b3 = ((const uint4*)bptr)[3];

    f32x4 acc[4][2] = {};

    for (int kt = 0; kt < 16; ++kt) {
        const int cur = kt & 1;
        *((uint4*)&As[cur][arow][acol])    = a0;
        *((uint4*)&As[cur][arow][acol+8])  = a1;
        *((uint4*)&Bs[cur][brow][bcol])    = b0;
        *((uint4*)&Bs[cur][brow][bcol+8])  = b1;
        *((uint4*)&Bs[cur][brow][bcol+16]) = b2;
        *((uint4*)&Bs[cur][brow][bcol+24]) = b3;
        uint4 na0, na1, nb0, nb1, nb2, nb3;
        if (kt < 15) {
            const unsigned short* ap = aptr + (kt+1)*64;
            const unsigned short* bp = bptr + (kt+1)*64;
            na0 = ((const uint4*)ap)[0]; na1 = ((const uint4*)ap)[1];
            nb0 = ((const uint4*)bp)[0]; nb1 = ((const uint4*)bp)[1];
            nb2 = ((const uint4*)bp)[2]; nb3 = ((const uint4*)bp)[3];
        }
        __syncthreads();
        #pragma unroll
        for (int ks = 0; ks < 2; ++ks) {
            bf16x8 am[4], bn[2];
            #pragma unroll
            for (int i = 0; i < 4; ++i)
                am[i] = *(const bf16x8*)&As[cur][i*16 + ln][ks*32 + quad*8];
            #pragma unroll
            for (int i = 0; i < 2; ++i)
                bn[i] = *(const bf16x8*)&Bs[cur][wave*32 + i*16 + ln][ks*32 + quad*8];
            #pragma unroll
            for (int mi = 0; mi < 4; ++mi)
                #pragma unroll
                for (int ni = 0; ni < 2; ++ni)
                    acc[mi][ni] = __builtin_amdgcn_mfma_f32_16x16x32_bf16(
                        am[mi], bn[ni], acc[mi][ni], 0,0,0);
        }
        a0 = na0; a1 = na1;
        b0 = nb0; b1 = nb1; b2 = nb2; b3 = nb3;
    }

    #pragma unroll
    for (int mi = 0; mi < 4; ++mi)
        #pragma unroll
        for (int ni = 0; ni < 2; ++ni) {
            int row = mt0*64 + mi*16 + quad*4;
            int col = nt0*128 + wave*32 + ni*16 + ln;
            float bv = bias[col];
            #pragma unroll
            for (int r = 0; r < 4; ++r)
                out[(size_t)(row + r)*1024 + col] = acc[mi][ni][r] + bv;
        }
}

// ---------------------------------------------------------------------------
extern "C" void kernel_launch(void* const* d_in, const int* in_sizes, int n_in,
                              void* d_out, int out_size, void* d_ws, size_t ws_size,
                              hipStream_t stream)
{
    const float* Q   = (const float*)d_in[0];
    const float* K   = (const float*)d_in[1];
    const float* V   = (const float*)d_in[2];
    const float* Wo  = (const float*)d_in[3];
    const float* Wb  = (const float*)d_in[4];
    const int* maskp = (const int*)d_in[5];
    float* out = (float*)d_out;

    // workspace layout (ushort units)
    unsigned short* Kf   = (unsigned short*)d_ws;              // 8.39 MB
    unsigned short* Vf   = Kf  + (size_t)B_*S_*D_;             // 8.39 MB
    unsigned short* Wob  = Vf  + (size_t)B_*S_*D_;             // 2.10 MB
    unsigned short* ctxb = Wob + (size_t)D_*D_;                // 8.39 MB
    float* Pv = (float*)(ctxb + (size_t)B_*S_*D_);             // 0.26 MB

    prep_kernel<<<3072, 256, 0, stream>>>(K, V, Wo, Kf, Vf, Wob, Pv);
    attn_kernel<<<1024, 256, 0, stream>>>(Q, Kf, Vf, Pv, ctxb, maskp);
    proj_kernel<<<dim3(8, 64), 256, 0, stream>>>(ctxb, Wob, Wb, out);
}

// Round 12
// 144.452 us; speedup vs baseline: 1.0144x; 1.0105x over previous
//
#include <hip/hip_runtime.h>
#include <hip/hip_bf16.h>
#include <stdint.h>

// Problem constants
#define B_  2
#define S_  2048
#define D_  1024
#define H_  16
#define DQ_ 64
#define QT_ (S_/64)   // 32 q-tiles (64 rows each) per (b,h)

// softmax is shift-invariant -> no max subtraction needed at all.
// scale folded into Q pack: qb = bf16(q * 0.125 * log2(e)), P = exp2(K·qb)
#define C1_ 0.18033688011112042f   // 0.125 * log2(e)

typedef float f32x4  __attribute__((ext_vector_type(4)));
typedef float f32x16 __attribute__((ext_vector_type(16)));
typedef short bf16x8 __attribute__((ext_vector_type(8)));

__device__ __forceinline__ unsigned short f2bf(float f) {
    uint32_t u = __float_as_uint(f);
    u += 0x7fffu + ((u >> 16) & 1u);   // round-to-nearest-even
    return (unsigned short)(u >> 16);
}
__device__ __forceinline__ float bf2f(unsigned short u) {
    return __uint_as_float(((uint32_t)u) << 16);
}
__device__ __forceinline__ float fast_exp2(float x) {
#if __has_builtin(__builtin_amdgcn_exp2f)
    return __builtin_amdgcn_exp2f(x);
#else
    float r; asm("v_exp_f32 %0, %1" : "=v"(r) : "v"(x)); return r;
#endif
}
__device__ __forceinline__ uint32_t cvt_pk_bf16(float lo, float hi) {
    uint32_t r;
    asm("v_cvt_pk_bf16_f32 %0, %1, %2" : "=v"(r) : "v"(lo), "v"(hi));
    return r;
}
// vdst[32..63] <-> vsrc[0..31]
__device__ __forceinline__ void permlane32_swap(uint32_t &a, uint32_t &b) {
    asm volatile("v_permlane32_swap_b32 %0, %1" : "+v"(a), "+v"(b));
}

// ---------------------------------------------------------------------------
// Kernel 1: prep. K/V -> exact 32x32x16 fragment order via LDS-staged
// transpose so BOTH the global loads (row-segmented float4) and the fragment
// stores (consecutive tid -> consecutive 16B) are fully coalesced. Also Wo
// fp32->bf16 and Pv column partials (row-0 mean(V)).
// ---------------------------------------------------------------------------
__global__ __launch_bounds__(256) void prep_kernel(
    const float* __restrict__ K, const float* __restrict__ V,
    const float* __restrict__ W,
    unsigned short* __restrict__ Kf, unsigned short* __restrict__ Vf,
    unsigned short* __restrict__ Wb, float* __restrict__ Pv)
{
    __shared__ unsigned short Ls[64][72];
    __shared__ float Pp[8][64];
    const int blk = blockIdx.x, tid = threadIdx.x;

    if (blk < 2048) {
        const bool isV = blk < 1024;
        const int gb = isV ? blk : (blk - 1024);
        const int g = gb >> 5, j = gb & 31;
        const int b = g >> 4, h = g & 15;
        const float* src0 = (isV ? V : K) + ((size_t)(b*S_ + j*64))*D_ + h*64;

        // phase A: coalesced tile load (64 rows x 64 cols fp32) -> bf16 LDS
        {
            int row = tid >> 2, col0 = (tid & 3) * 16;
            const float* src = src0 + (size_t)row*D_ + col0;
            float4 f0 = ((const float4*)src)[0];
            float4 f1 = ((const float4*)src)[1];
            float4 f2 = ((const float4*)src)[2];
            float4 f3 = ((const float4*)src)[3];
            unsigned short* d = &Ls[row][col0];
            d[0]=f2bf(f0.x); d[1]=f2bf(f0.y); d[2]=f2bf(f0.z); d[3]=f2bf(f0.w);
            d[4]=f2bf(f1.x); d[5]=f2bf(f1.y); d[6]=f2bf(f1.z); d[7]=f2bf(f1.w);
            d[8]=f2bf(f2.x); d[9]=f2bf(f2.y); d[10]=f2bf(f2.z); d[11]=f2bf(f2.w);
            d[12]=f2bf(f3.x); d[13]=f2bf(f3.y); d[14]=f2bf(f3.z); d[15]=f2bf(f3.w);
        }
        __syncthreads();

        if (isV) {
            // phase B: transpose via LDS scalar reads -> coalesced frag stores
            #pragma unroll
            for (int ps = 0; ps < 2; ++ps) {
                const int slot = tid + ps*256;
                const int fb = slot >> 6, l = slot & 63;
                const int s = fb >> 1, kk = fb & 1;
                const int hi = l >> 5, l31 = l & 31;
                const int dcol = kk*32 + l31;
                unsigned short us[8];
                float p = 0.f;
                #pragma unroll
                for (int r = 0; r < 8; ++r) {
                    unsigned short u = Ls[s*16 + hi*8 + r][dcol];
                    us[r] = u;
                    p += bf2f(u);
                }
                *(uint4*)(Vf + ((size_t)gb*8 + fb)*512 + (size_t)l*8) = *(uint4*)us;
                Pp[s*2 + hi][dcol] = p;
            }
            __syncthreads();
            if (tid < 64) {
                float t = 0.f;
                #pragma unroll
                for (int i = 0; i < 8; ++i) t += Pp[i][tid];
                Pv[((size_t)g*64 + tid)*32 + j] = t;
            }
        } else {
            // phase B: rows are fragment-contiguous -> b128 LDS reads
            #pragma unroll
            for (int ps = 0; ps < 2; ++ps) {
                const int slot = tid + ps*256;
                const int fb = slot >> 6, l = slot & 63;
                const int wk = fb >> 2, s = fb & 3;
                const int hi = l >> 5, l31 = l & 31;
                uint4 val = *(const uint4*)&Ls[wk*32 + l31][s*16 + hi*8];
                *(uint4*)(Kf + ((size_t)gb*8 + fb)*512 + (size_t)l*8) = val;
            }
        }
    } else {
        int i = (blk - 2048)*256 + tid;     // < D*D/4 = 262144
        float4 f = ((const float4*)W)[i];
        ushort4 o;
        o.x = f2bf(f.x); o.y = f2bf(f.y); o.z = f2bf(f.z); o.w = f2bf(f.w);
        ((ushort4*)Wb)[i] = o;
    }
}

// ---------------------------------------------------------------------------
// Kernel 2: flash attention, 32x32x16 MFMA, zero-LDS main loop. Best-measured
// configuration of the session (R9, 143.4us total). Depth-3 prefetch
// (unroll-3 rotation), two parallel QK chains, 4 independent PV accumulators,
// longest-first balanced qt map, Q staged via LDS, setprio, shift-free
// softmax, per-wave causal niter, bid&7 XCD affinity, single end barrier.
// launch_bounds (256,2): do NOT raise the 2nd arg (R4/R5: allocator spill).
// Session scorecard for the ~35us residual: occupancy (R6), chain depth (R8),
// prefetch distance (R9), L2 traffic (R10), cross-iter ILP (R11) all
// measured FLAT — kernel does not respond to any HIP-level structural lever.
// ---------------------------------------------------------------------------
__global__ __launch_bounds__(256, 2) void attn_kernel(
    const float* __restrict__ Q,
    const unsigned short* __restrict__ Kf,
    const unsigned short* __restrict__ Vf,
    const float* __restrict__ Pv,
    unsigned short* __restrict__ ctx,
    const int* __restrict__ maskp)
{
    __shared__ union {
        unsigned short qs[64][72];                    // Q staging (prologue)
        struct { float osum[2][32][68]; float lsum[2][32]; } red;  // epilogue
    } sm;

    const int bid = blockIdx.x;
    const int g = bid & 31;             // h + 16*b ; g&7 = bid&7 -> XCD
    const int p = bid >> 5;             // [0,32)
    // longest-first balanced permutation: octiles -> qt {31..24,16..23,15..8,0..7}
    const int qt = (p < 8) ? 31 - p : (p < 16) ? p + 8 : (p < 24) ? 31 - p : p - 24;
    const int h = g & 15, b = g >> 4;
    const int tid  = threadIdx.x;
    const int wave = tid >> 6, lane = tid & 63;
    const int wq = wave >> 1, wk = wave & 1;
    const int hi = lane >> 5, l31 = lane & 31;
    const int maskv = maskp[0];

    // fused mean(V) -> ctx row 0, cols [h*64, h*64+64)
    if (maskv && qt == 0 && tid < 64) {
        const float* pv = Pv + ((size_t)g*64 + tid)*32;
        float s = 0.f;
        #pragma unroll
        for (int i = 0; i < 32; ++i) s += pv[i];
        ctx[(size_t)b*S_*D_ + h*64 + tid] = f2bf(s * (1.0f/S_));
    }

    // ---- stage Q tile (coalesced) -> LDS as pre-scaled bf16 ----
    {
        const int row = tid >> 2, col0 = (tid & 3) * 16;
        const float* src = Q + ((size_t)(b*S_ + qt*64 + row))*D_ + h*64 + col0;
        float4 f0 = ((const float4*)src)[0];
        float4 f1 = ((const float4*)src)[1];
        float4 f2 = ((const float4*)src)[2];
        float4 f3 = ((const float4*)src)[3];
        unsigned short* d = &sm.qs[row][col0];
        d[0]=f2bf(f0.x*C1_); d[1]=f2bf(f0.y*C1_); d[2]=f2bf(f0.z*C1_); d[3]=f2bf(f0.w*C1_);
        d[4]=f2bf(f1.x*C1_); d[5]=f2bf(f1.y*C1_); d[6]=f2bf(f1.z*C1_); d[7]=f2bf(f1.w*C1_);
        d[8]=f2bf(f2.x*C1_); d[9]=f2bf(f2.y*C1_); d[10]=f2bf(f2.z*C1_); d[11]=f2bf(f2.w*C1_);
        d[12]=f2bf(f3.x*C1_); d[13]=f2bf(f3.y*C1_); d[14]=f2bf(f3.z*C1_); d[15]=f2bf(f3.w*C1_);
    }
    __syncthreads();
    bf16x8 qf[4];
    #pragma unroll
    for (int s = 0; s < 4; ++s)
        qf[s] = *(const bf16x8*)&sm.qs[wq*32 + l31][s*16 + hi*8];
    __syncthreads();   // Qs reads done before epilogue aliases the buffer

    // fragment bases (advance by j*4096 ushorts per tile)
    const unsigned short* kfb =
        Kf + ((size_t)g*32*8 + wk*4)*512 + (size_t)lane*8;
    const unsigned short* vfb =
        Vf + ((size_t)g*32*8 + wk*4)*512 + (size_t)lane*8;

    int njw = maskv ? (qt + 1) : QT_;
    if (maskv && wq == 0 && wk == 1) njw = qt;  // diagonal tile fully masked

    // 4 independent PV accumulators (summed in the epilogue)
    f32x16 o00 = {}, o01 = {}, o10 = {}, o11 = {};
    float lsum = 0.f;

    // ---- depth-3 prefetch: static 3-buffer rotation (no runtime idx)
    bf16x8 ka[4], va[4], kb[4], vb[4], kc3[4], vc3[4];
    if (njw > 0) {
        #pragma unroll
        for (int s = 0; s < 4; ++s) {
            ka[s] = *(const bf16x8*)(kfb + s*512);
            va[s] = *(const bf16x8*)(vfb + s*512);
        }
    }
    if (njw > 1) {
        #pragma unroll
        for (int s = 0; s < 4; ++s) {
            kb[s] = *(const bf16x8*)(kfb + 4096 + s*512);
            vb[s] = *(const bf16x8*)(vfb + 4096 + s*512);
        }
    }
    if (njw > 2) {
        #pragma unroll
        for (int s = 0; s < 4; ++s) {
            kc3[s] = *(const bf16x8*)(kfb + 8192 + s*512);
            vc3[s] = *(const bf16x8*)(vfb + 8192 + s*512);
        }
    }

#define AITER(J, KC, VC)                                                      \
  {                                                                           \
    f32x16 st0 = {}, st1 = {};       /* two parallel 2-deep QK chains */      \
    __builtin_amdgcn_s_setprio(1);                                            \
    st0 = __builtin_amdgcn_mfma_f32_32x32x16_bf16(KC[0], qf[0], st0, 0,0,0);  \
    st1 = __builtin_amdgcn_mfma_f32_32x32x16_bf16(KC[1], qf[1], st1, 0,0,0);  \
    st0 = __builtin_amdgcn_mfma_f32_32x32x16_bf16(KC[2], qf[2], st0, 0,0,0);  \
    st1 = __builtin_amdgcn_mfma_f32_32x32x16_bf16(KC[3], qf[3], st1, 0,0,0);  \
    __builtin_amdgcn_s_setprio(0);                                            \
    if ((J) + 3 < njw) {   /* reload just-consumed K buffer for j+3 */        \
      const unsigned short* kp_ = kfb + (size_t)((J)+3)*4096;                 \
      KC[0] = *(const bf16x8*)(kp_);                                          \
      KC[1] = *(const bf16x8*)(kp_ + 512);                                    \
      KC[2] = *(const bf16x8*)(kp_ + 1024);                                   \
      KC[3] = *(const bf16x8*)(kp_ + 1536);                                   \
    }                                                                         \
    f32x16 st = st0 + st1;                                                    \
    float e[16];                                                              \
    const bool diag_ = maskv && ((J) == qt) && (wk == wq);                    \
    if (diag_) {                                                              \
      _Pragma("unroll")                                                       \
      for (int r = 0; r < 16; ++r) {                                          \
        int kr_ = (r&3) + 8*(r>>2) + 4*hi;                                    \
        float ev_ = fast_exp2(st[r]);                                         \
        e[r] = (kr_ >= l31) ? 0.f : ev_;                                      \
        lsum += e[r];                                                         \
      }                                                                       \
    } else {                                                                  \
      _Pragma("unroll")                                                       \
      for (int r = 0; r < 16; ++r) { e[r] = fast_exp2(st[r]); lsum += e[r]; } \
    }                                                                         \
    uint32_t p01_ = cvt_pk_bf16(e[0], e[1]),  p23_ = cvt_pk_bf16(e[2], e[3]); \
    uint32_t p45_ = cvt_pk_bf16(e[4], e[5]),  p67_ = cvt_pk_bf16(e[6], e[7]); \
    permlane32_swap(p01_, p45_); permlane32_swap(p23_, p67_);                 \
    uint32_t r01_ = cvt_pk_bf16(e[8], e[9]),  r23_ = cvt_pk_bf16(e[10], e[11]); \
    uint32_t r45_ = cvt_pk_bf16(e[12], e[13]), r67_ = cvt_pk_bf16(e[14], e[15]); \
    permlane32_swap(r01_, r45_); permlane32_swap(r23_, r67_);                 \
    union { uint32_t u[4]; bf16x8 v; } A0_, A1_;                              \
    A0_.u[0]=p01_; A0_.u[1]=p23_; A0_.u[2]=p45_; A0_.u[3]=p67_;               \
    A1_.u[0]=r01_; A1_.u[1]=r23_; A1_.u[2]=r45_; A1_.u[3]=r67_;               \
    __builtin_amdgcn_s_setprio(1);   /* 4 INDEPENDENT PV MFMAs */             \
    o00 = __builtin_amdgcn_mfma_f32_32x32x16_bf16(A0_.v, VC[0], o00, 0,0,0);  \
    o10 = __builtin_amdgcn_mfma_f32_32x32x16_bf16(A0_.v, VC[1], o10, 0,0,0);  \
    o01 = __builtin_amdgcn_mfma_f32_32x32x16_bf16(A1_.v, VC[2], o01, 0,0,0);  \
    o11 = __builtin_amdgcn_mfma_f32_32x32x16_bf16(A1_.v, VC[3], o11, 0,0,0);  \
    __builtin_amdgcn_s_setprio(0);                                            \
    if ((J) + 3 < njw) {   /* reload just-consumed V buffer for j+3 */        \
      const unsigned short* vp_ = vfb + (size_t)((J)+3)*4096;                 \
      VC[0] = *(const bf16x8*)(vp_);                                          \
      VC[1] = *(const bf16x8*)(vp_ + 512);                                    \
      VC[2] = *(const bf16x8*)(vp_ + 1024);                                   \
      VC[3] = *(const bf16x8*)(vp_ + 1536);                                   \
    }                                                                         \
  }

    int j = 0;
    for (; j + 2 < njw; j += 3) {
        AITER(j,   ka,  va);
        AITER(j+1, kb,  vb);
        AITER(j+2, kc3, vc3);
    }
    if (j < njw)     AITER(j,   ka, va);
    if (j+1 < njw)   AITER(j+1, kb, vb);
#undef AITER

    f32x16 o0 = o00 + o01;     // combine split PV accumulators
    f32x16 o1 = o10 + o11;

    // ---- cross-wk reduction + epilogue (one barrier) ----
    lsum += __shfl_xor(lsum, 32);   // combine hi/lo key quads: l for q=l31

    if (wk == 1) {
        #pragma unroll
        for (int r = 0; r < 16; ++r) {
            int qr = (r&3) + 8*(r>>2) + 4*hi;
            sm.red.osum[wq][qr][l31]      = o0[r];
            sm.red.osum[wq][qr][32 + l31] = o1[r];
        }
        if (hi == 0) sm.red.lsum[wq][l31] = lsum;
    }
    __syncthreads();
    if (wk == 0) {
        float inv = 1.0f / (lsum + sm.red.lsum[wq][l31]);   // inv for q = l31
        #pragma unroll
        for (int r = 0; r < 16; ++r) {
            int qr = (r&3) + 8*(r>>2) + 4*hi;
            float o0v = o0[r] + sm.red.osum[wq][qr][l31];
            float o1v = o1[r] + sm.red.osum[wq][qr][32 + l31];
            float invr = __shfl(inv, qr);
            int q = qt*64 + wq*32 + qr;
            if (!(maskv && q == 0)) {   // row 0 = mean(V), done above
                size_t base = ((size_t)(b*S_ + q))*D_ + h*64;
                ctx[base + l31]      = f2bf(o0v * invr);
                ctx[base + 32 + l31] = f2bf(o1v * invr);
            }
        }
    }
}

// ---------------------------------------------------------------------------
// Kernel 3: out = ctx @ Wo^T + bias   (M=4096, N=1024, K=1024, bf16 MFMA)
// 64x128 tile, 4 waves (each 64x32), BK=64, double-buffered, 1 barrier/kt.
// Grid (8, 64) = 512 blocks -> 2 blocks/CU; bid%8 = nt0 -> each XCD caches
// exactly one 128-col Wo panel (0.25 MB).
// ---------------------------------------------------------------------------
__global__ __launch_bounds__(256, 2) void proj_kernel(
    const unsigned short* __restrict__ A,    // ctx bf16 [4096][1024]
    const unsigned short* __restrict__ Bw,   // Wo bf16  [1024][1024]
    const float* __restrict__ bias,
    float* __restrict__ out)
{
    __shared__ unsigned short As[2][64][72];
    __shared__ unsigned short Bs[2][128][72];
    const int nt0 = blockIdx.x;   // 0..7   (N panel)
    const int mt0 = blockIdx.y;   // 0..63  (M panel)
    const int tid  = threadIdx.x;
    const int wave = tid >> 6, lane = tid & 63;
    const int quad = lane >> 4, ln = lane & 15;

    const int arow = tid >> 2, acol = (tid & 3)*16;   // A: 64 rows x 64 cols
    const int brow = tid >> 1, bcol = (tid & 1)*32;   // B: 128 rows x 64 cols
    const unsigned short* aptr = A  + ((size_t)(mt0*64  + arow)*1024 + acol);
    const unsigned short* bptr = Bw + ((size_t)(nt0*128 + brow)*1024 + bcol);

    uint4 a0 = ((const uint4*)aptr)[0], a1 = ((const uint4*)aptr)[1];
    uint4 b0 = ((const uint4*)bptr)[0], b1 = ((const uint4*)bptr)[1],
          b2 = ((const uint4*)bptr)[2], b3 = ((const uint4*)bptr)[3];

    f32x4 acc[4][2] = {};

    for (int kt = 0; kt < 16; ++kt) {
        const int cur = kt & 1;
        *((uint4*)&As[cur][arow][acol])    = a0;
        *((uint4*)&As[cur][arow][acol+8])  = a1;
        *((uint4*)&Bs[cur][brow][bcol])    = b0;
        *((uint4*)&Bs[cur][brow][bcol+8])  = b1;
        *((uint4*)&Bs[cur][brow][bcol+16]) = b2;
        *((uint4*)&Bs[cur][brow][bcol+24]) = b3;
        uint4 na0, na1, nb0, nb1, nb2, nb3;
        if (kt < 15) {
            const unsigned short* ap = aptr + (kt+1)*64;
            const unsigned short* bp = bptr + (kt+1)*64;
            na0 = ((const uint4*)ap)[0]; na1 = ((const uint4*)ap)[1];
            nb0 = ((const uint4*)bp)[0]; nb1 = ((const uint4*)bp)[1];
            nb2 = ((const uint4*)bp)[2]; nb3 = ((const uint4*)bp)[3];
        }
        __syncthreads();
        #pragma unroll
        for (int ks = 0; ks < 2; ++ks) {
            bf16x8 am[4], bn[2];
            #pragma unroll
            for (int i = 0; i < 4; ++i)
                am[i] = *(const bf16x8*)&As[cur][i*16 + ln][ks*32 + quad*8];
            #pragma unroll
            for (int i = 0; i < 2; ++i)
                bn[i] = *(const bf16x8*)&Bs[cur][wave*32 + i*16 + ln][ks*32 + quad*8];
            #pragma unroll
            for (int mi = 0; mi < 4; ++mi)
                #pragma unroll
                for (int ni = 0; ni < 2; ++ni)
                    acc[mi][ni] = __builtin_amdgcn_mfma_f32_16x16x32_bf16(
                        am[mi], bn[ni], acc[mi][ni], 0,0,0);
        }
        a0 = na0; a1 = na1;
        b0 = nb0; b1 = nb1; b2 = nb2; b3 = nb3;
    }

    #pragma unroll
    for (int mi = 0; mi < 4; ++mi)
        #pragma unroll
        for (int ni = 0; ni < 2; ++ni) {
            int row = mt0*64 + mi*16 + quad*4;
            int col = nt0*128 + wave*32 + ni*16 + ln;
            float bv = bias[col];
            #pragma unroll
            for (int r = 0; r < 4; ++r)
                out[(size_t)(row + r)*1024 + col] = acc[mi][ni][r] + bv;
        }
}

// ---------------------------------------------------------------------------
extern "C" void kernel_launch(void* const* d_in, const int* in_sizes, int n_in,
                              void* d_out, int out_size, void* d_ws, size_t ws_size,
                              hipStream_t stream)
{
    const float* Q   = (const float*)d_in[0];
    const float* K   = (const float*)d_in[1];
    const float* V   = (const float*)d_in[2];
    const float* Wo  = (const float*)d_in[3];
    const float* Wb  = (const float*)d_in[4];
    const int* maskp = (const int*)d_in[5];
    float* out = (float*)d_out;

    // workspace layout (ushort units)
    unsigned short* Kf   = (unsigned short*)d_ws;              // 8.39 MB
    unsigned short* Vf   = Kf  + (size_t)B_*S_*D_;             // 8.39 MB
    unsigned short* Wob  = Vf  + (size_t)B_*S_*D_;             // 2.10 MB
    unsigned short* ctxb = Wob + (size_t)D_*D_;                // 8.39 MB
    float* Pv = (float*)(ctxb + (size_t)B_*S_*D_);             // 0.26 MB

    prep_kernel<<<3072, 256, 0, stream>>>(K, V, Wo, Kf, Vf, Wob, Pv);
    attn_kernel<<<1024, 256, 0, stream>>>(Q, Kf, Vf, Pv, ctxb, maskp);
    proj_kernel<<<dim3(8, 64), 256, 0, stream>>>(ctxb, Wob, Wb, out);
}